// Round 1
// baseline (1263.757 us; speedup 1.0000x reference)
//
#include <hip/hip_runtime.h>
#include <stdint.h>

#define B_ 16
#define N_ 2048
#define V_ 1024

typedef __bf16 bf16x8 __attribute__((ext_vector_type(8)));
typedef float  f32x4  __attribute__((ext_vector_type(4)));

__device__ __forceinline__ unsigned short f2bf(float f) {
    union { float f; uint32_t u; } c; c.f = f;
    uint32_t r = c.u + 0x7fffu + ((c.u >> 16) & 1u);   // RNE
    return (unsigned short)(r >> 16);
}
__device__ __forceinline__ float bf2f(unsigned short h) {
    union { uint32_t u; float f; } c; c.u = ((uint32_t)h) << 16;
    return c.f;
}
__device__ __forceinline__ void gld_lds16(const void* g, void* l) {
    __builtin_amdgcn_global_load_lds(
        (const __attribute__((address_space(1))) void*)g,
        (__attribute__((address_space(3))) void*)l, 16, 0, 0);
}

// ---------------- K0: fT[b][v][m] = bf16(features[b][m][v]) ----------------
__global__ __launch_bounds__(256) void k0_transpose(
    const float* __restrict__ feat, unsigned short* __restrict__ fT)
{
    __shared__ __align__(16) unsigned short T[64 * 66];  // stride 66 breaks bank conflicts
    const int b  = blockIdx.y;
    const int tm = blockIdx.x & 31, tv = blockIdx.x >> 5;
    const int m0 = tm * 64, v0 = tv * 64;
    const size_t bN = (size_t)b * N_;
    const int tid = threadIdx.x;

    for (int it = 0; it < 4; ++it) {
        int idx = tid + 256 * it;
        int mm = idx >> 4, vseg = idx & 15;
        float4 f4 = *(const float4*)(feat + (bN + m0 + mm) * V_ + v0 + vseg * 4);
        *(ushort2*)&T[mm * 66 + vseg * 4]     = make_ushort2(f2bf(f4.x), f2bf(f4.y));
        *(ushort2*)&T[mm * 66 + vseg * 4 + 2] = make_ushort2(f2bf(f4.z), f2bf(f4.w));
    }
    __syncthreads();
    for (int it = 0; it < 2; ++it) {
        int idx = tid + 256 * it;
        int vv = idx >> 3, mseg = idx & 7;
        uint4 pk;
        unsigned short* pp = (unsigned short*)&pk;
        #pragma unroll
        for (int j = 0; j < 8; ++j) pp[j] = T[(mseg * 8 + j) * 66 + vv];
        *(uint4*)&fT[(size_t)b * V_ * N_ + (size_t)(v0 + vv) * N_ + m0 + mseg * 8] = pk;
    }
}

// ---------------- K1: x = feat @ W^T + b, split-bf16 (hi/lo), out x_hi/x_lo ----------------
__global__ __launch_bounds__(256, 2) void k1_xgemm(
    const float* __restrict__ feat, const float* __restrict__ W,
    const float* __restrict__ bias,
    unsigned short* __restrict__ x_hi, unsigned short* __restrict__ x_lo)
{
    __shared__ __align__(16) unsigned short Ah[128 * 64], Al[128 * 64], Bh[128 * 64], Bl[128 * 64];
    const int tid = threadIdx.x;
    const int lane = tid & 63, wid = tid >> 6;
    const int wr = wid >> 1, wc = wid & 1;
    const int l15 = lane & 15, lg = lane >> 4;
    const size_t gm0 = (size_t)blockIdx.x * 128;
    const int o0 = blockIdx.y * 128;

    f32x4 acc[4][4];
    #pragma unroll
    for (int i = 0; i < 4; ++i)
        #pragma unroll
        for (int j = 0; j < 4; ++j) acc[i][j] = (f32x4)(0.0f);

    for (int kk = 0; kk < V_; kk += 64) {
        #pragma unroll
        for (int it = 0; it < 8; ++it) {
            int idx = tid + 256 * it;
            int row = idx >> 4, seg = idx & 15;
            float4 fa = *(const float4*)(feat + (gm0 + row) * V_ + kk + seg * 4);
            unsigned short h0 = f2bf(fa.x), h1 = f2bf(fa.y), h2 = f2bf(fa.z), h3 = f2bf(fa.w);
            *(ushort4*)&Ah[row * 64 + seg * 4] = make_ushort4(h0, h1, h2, h3);
            *(ushort4*)&Al[row * 64 + seg * 4] = make_ushort4(
                f2bf(fa.x - bf2f(h0)), f2bf(fa.y - bf2f(h1)),
                f2bf(fa.z - bf2f(h2)), f2bf(fa.w - bf2f(h3)));
            float4 fb = *(const float4*)(W + (size_t)(o0 + row) * V_ + kk + seg * 4);
            unsigned short g0 = f2bf(fb.x), g1 = f2bf(fb.y), g2 = f2bf(fb.z), g3 = f2bf(fb.w);
            *(ushort4*)&Bh[row * 64 + seg * 4] = make_ushort4(g0, g1, g2, g3);
            *(ushort4*)&Bl[row * 64 + seg * 4] = make_ushort4(
                f2bf(fb.x - bf2f(g0)), f2bf(fb.y - bf2f(g1)),
                f2bf(fb.z - bf2f(g2)), f2bf(fb.w - bf2f(g3)));
        }
        __syncthreads();
        #pragma unroll
        for (int kq = 0; kq < 2; ++kq) {
            bf16x8 ah[4], al[4], bh[4], bl[4];
            #pragma unroll
            for (int i = 0; i < 4; ++i) {
                int ra = wr * 64 + i * 16 + l15;
                ah[i] = *(const bf16x8*)&Ah[ra * 64 + kq * 32 + lg * 8];
                al[i] = *(const bf16x8*)&Al[ra * 64 + kq * 32 + lg * 8];
                int rb = wc * 64 + i * 16 + l15;
                bh[i] = *(const bf16x8*)&Bh[rb * 64 + kq * 32 + lg * 8];
                bl[i] = *(const bf16x8*)&Bl[rb * 64 + kq * 32 + lg * 8];
            }
            #pragma unroll
            for (int i = 0; i < 4; ++i)
                #pragma unroll
                for (int j = 0; j < 4; ++j) {
                    acc[i][j] = __builtin_amdgcn_mfma_f32_16x16x32_bf16(ah[i], bh[j], acc[i][j], 0, 0, 0);
                    acc[i][j] = __builtin_amdgcn_mfma_f32_16x16x32_bf16(al[i], bh[j], acc[i][j], 0, 0, 0);
                    acc[i][j] = __builtin_amdgcn_mfma_f32_16x16x32_bf16(ah[i], bl[j], acc[i][j], 0, 0, 0);
                }
        }
        __syncthreads();
    }
    #pragma unroll
    for (int j = 0; j < 4; ++j) {
        int oc = o0 + wc * 64 + j * 16 + l15;
        float bv = bias[oc];
        #pragma unroll
        for (int i = 0; i < 4; ++i)
            #pragma unroll
            for (int r = 0; r < 4; ++r) {
                size_t gm = gm0 + wr * 64 + i * 16 + 4 * lg + r;
                float v = acc[i][j][r] + bv;
                unsigned short h = f2bf(v);
                x_hi[gm * V_ + oc] = h;
                x_lo[gm * V_ + oc] = f2bf(v - bf2f(h));
            }
    }
}

// ---------------- K2: P = mask * exp(tanh(x f^T)), rowsum += ----------------
__global__ __launch_bounds__(256, 2) void k2_scores(
    const float* __restrict__ feat,
    const unsigned short* __restrict__ x_hi, const unsigned short* __restrict__ x_lo,
    const int* __restrict__ lengths,
    unsigned short* __restrict__ P, float* __restrict__ rowsum)
{
    __shared__ __align__(16) unsigned short Ah[128 * 64], Al[128 * 64], Bh[128 * 64], Bl[128 * 64];
    const int b = blockIdx.y;
    const int tn = blockIdx.x & 15, tm = blockIdx.x >> 4;
    const int n0 = tn * 128, m0 = tm * 128;
    const int len = lengths[b];
    const int m_end = min(n0 + 128, len);
    if (m0 >= m_end) return;  // tile fully masked (uniform exit, before barriers)

    const int tid = threadIdx.x;
    const int lane = tid & 63, wid = tid >> 6;
    const int wr = wid >> 1, wc = wid & 1;
    const int l15 = lane & 15, lg = lane >> 4;
    const size_t bN = (size_t)b * N_;

    f32x4 acc[4][4];
    #pragma unroll
    for (int i = 0; i < 4; ++i)
        #pragma unroll
        for (int j = 0; j < 4; ++j) acc[i][j] = (f32x4)(0.0f);

    for (int kk = 0; kk < V_; kk += 64) {
        // A: x_hi/x_lo via async global->LDS (linear dest, 16B/lane)
        #pragma unroll
        for (int i = 0; i < 4; ++i) {
            int chunk = wid * 4 + i;
            int lidx = chunk * 64 + lane;
            int row = lidx >> 3, seg = lidx & 7;
            gld_lds16(x_hi + (bN + n0 + row) * V_ + kk + seg * 8, &Ah[chunk * 512]);
            gld_lds16(x_lo + (bN + n0 + row) * V_ + kk + seg * 8, &Al[chunk * 512]);
        }
        // B: features fp32 -> hi/lo split in LDS
        #pragma unroll
        for (int it = 0; it < 8; ++it) {
            int idx = tid + 256 * it;
            int row = idx >> 4, seg = idx & 15;
            float4 fb = *(const float4*)(feat + (bN + m0 + row) * V_ + kk + seg * 4);
            unsigned short g0 = f2bf(fb.x), g1 = f2bf(fb.y), g2 = f2bf(fb.z), g3 = f2bf(fb.w);
            *(ushort4*)&Bh[row * 64 + seg * 4] = make_ushort4(g0, g1, g2, g3);
            *(ushort4*)&Bl[row * 64 + seg * 4] = make_ushort4(
                f2bf(fb.x - bf2f(g0)), f2bf(fb.y - bf2f(g1)),
                f2bf(fb.z - bf2f(g2)), f2bf(fb.w - bf2f(g3)));
        }
        __syncthreads();
        #pragma unroll
        for (int kq = 0; kq < 2; ++kq) {
            bf16x8 ah[4], al[4], bh[4], bl[4];
            #pragma unroll
            for (int i = 0; i < 4; ++i) {
                int ra = wr * 64 + i * 16 + l15;
                ah[i] = *(const bf16x8*)&Ah[ra * 64 + kq * 32 + lg * 8];
                al[i] = *(const bf16x8*)&Al[ra * 64 + kq * 32 + lg * 8];
                int rb = wc * 64 + i * 16 + l15;
                bh[i] = *(const bf16x8*)&Bh[rb * 64 + kq * 32 + lg * 8];
                bl[i] = *(const bf16x8*)&Bl[rb * 64 + kq * 32 + lg * 8];
            }
            #pragma unroll
            for (int i = 0; i < 4; ++i)
                #pragma unroll
                for (int j = 0; j < 4; ++j) {
                    acc[i][j] = __builtin_amdgcn_mfma_f32_16x16x32_bf16(ah[i], bh[j], acc[i][j], 0, 0, 0);
                    acc[i][j] = __builtin_amdgcn_mfma_f32_16x16x32_bf16(al[i], bh[j], acc[i][j], 0, 0, 0);
                    acc[i][j] = __builtin_amdgcn_mfma_f32_16x16x32_bf16(ah[i], bl[j], acc[i][j], 0, 0, 0);
                }
        }
        __syncthreads();
    }

    // epilogue: p = exp(tanh(s)) masked; store bf16 P; accumulate fp32 rowsum
    unsigned short* Pb = P + (size_t)b * N_ * N_;
    #pragma unroll
    for (int i = 0; i < 4; ++i) {
        float prow[4] = {0.f, 0.f, 0.f, 0.f};
        #pragma unroll
        for (int j = 0; j < 4; ++j) {
            int mg = m0 + wc * 64 + j * 16 + l15;
            #pragma unroll
            for (int r = 0; r < 4; ++r) {
                int ng = n0 + wr * 64 + i * 16 + 4 * lg + r;
                float s = acc[i][j][r];
                float e2 = __expf(2.0f * fabsf(s));
                float t = 1.0f - __fdividef(2.0f, e2 + 1.0f);   // tanh(|s|), exact at inf
                t = (s < 0.0f) ? -t : t;
                float p = __expf(t);
                bool keep = (mg <= ng) && (mg < len);
                p = keep ? p : 0.0f;
                unsigned short ph = f2bf(p);
                Pb[(size_t)ng * N_ + mg] = ph;
                prow[r] += bf2f(ph);   // sum the ROUNDED value so weights renormalize exactly
            }
        }
        #pragma unroll
        for (int r = 0; r < 4; ++r) {
            float v = prow[r];
            v += __shfl_xor(v, 1); v += __shfl_xor(v, 2);
            v += __shfl_xor(v, 4); v += __shfl_xor(v, 8);
            if (l15 == 0) {
                int ng = n0 + wr * 64 + i * 16 + 4 * lg + r;
                atomicAdd(&rowsum[bN + ng], v);
            }
        }
    }
}

// ---------------- K3: out = (P @ f) / rowsum ----------------
__global__ __launch_bounds__(256, 2) void k3_pv(
    const unsigned short* __restrict__ P, const unsigned short* __restrict__ fT,
    const float* __restrict__ rowsum, const int* __restrict__ lengths,
    float* __restrict__ out)
{
    __shared__ __align__(16) unsigned short Ap[128 * 64], Bp[128 * 64];
    const int b = blockIdx.y;
    const int tn = blockIdx.x & 15, tv = blockIdx.x >> 4;
    const int n0 = tn * 128, v0 = tv * 128;
    const int len = lengths[b];
    const int m_end = min(n0 + 128, len);
    const int nk = (m_end + 63) >> 6;
    const size_t bN = (size_t)b * N_;
    const unsigned short* Pb  = P  + (size_t)b * N_ * N_;
    const unsigned short* fTb = fT + (size_t)b * V_ * N_;

    const int tid = threadIdx.x;
    const int lane = tid & 63, wid = tid >> 6;
    const int wr = wid >> 1, wc = wid & 1;
    const int l15 = lane & 15, lg = lane >> 4;

    f32x4 acc[4][4];
    #pragma unroll
    for (int i = 0; i < 4; ++i)
        #pragma unroll
        for (int j = 0; j < 4; ++j) acc[i][j] = (f32x4)(0.0f);

    for (int kt = 0; kt < nk; ++kt) {
        int k0 = kt * 64;
        #pragma unroll
        for (int i = 0; i < 4; ++i) {
            int chunk = wid * 4 + i;
            int lidx = chunk * 64 + lane;
            int row = lidx >> 3, seg = lidx & 7;
            gld_lds16(Pb  + (size_t)(n0 + row) * N_ + k0 + seg * 8, &Ap[chunk * 512]);
            gld_lds16(fTb + (size_t)(v0 + row) * N_ + k0 + seg * 8, &Bp[chunk * 512]);
        }
        __syncthreads();
        #pragma unroll
        for (int kq = 0; kq < 2; ++kq) {
            bf16x8 a[4], bb[4];
            #pragma unroll
            for (int i = 0; i < 4; ++i) {
                int ra = wr * 64 + i * 16 + l15;
                a[i]  = *(const bf16x8*)&Ap[ra * 64 + kq * 32 + lg * 8];
                int rb = wc * 64 + i * 16 + l15;
                bb[i] = *(const bf16x8*)&Bp[rb * 64 + kq * 32 + lg * 8];
            }
            #pragma unroll
            for (int i = 0; i < 4; ++i)
                #pragma unroll
                for (int j = 0; j < 4; ++j)
                    acc[i][j] = __builtin_amdgcn_mfma_f32_16x16x32_bf16(a[i], bb[j], acc[i][j], 0, 0, 0);
        }
        __syncthreads();
    }

    #pragma unroll
    for (int i = 0; i < 4; ++i)
        #pragma unroll
        for (int r = 0; r < 4; ++r) {
            int ng = n0 + wr * 64 + i * 16 + 4 * lg + r;
            float rinv = 1.0f / rowsum[bN + ng];
            #pragma unroll
            for (int j = 0; j < 4; ++j) {
                int vg = v0 + wc * 64 + j * 16 + l15;
                out[(bN + ng) * (size_t)V_ + vg] = acc[i][j][r] * rinv;
            }
        }
}

extern "C" void kernel_launch(void* const* d_in, const int* in_sizes, int n_in,
                              void* d_out, int out_size, void* d_ws, size_t ws_size,
                              hipStream_t stream)
{
    const float* feat    = (const float*)d_in[0];
    const int*   lengths = (const int*)d_in[1];
    const float* W       = (const float*)d_in[2];
    const float* bias    = (const float*)d_in[3];
    float* out = (float*)d_out;

    char* ws = (char*)d_ws;
    // ws layout (bytes): x_hi 64MB | x_lo 64MB | P 128MB | fT 64MB | rowsum 128KB  (~336MB)
    unsigned short* x_hi = (unsigned short*)(ws);
    unsigned short* x_lo = (unsigned short*)(ws + 67108864);
    unsigned short* P    = (unsigned short*)(ws + 134217728);
    unsigned short* fT   = (unsigned short*)(ws + 268435456);
    float* rowsum        = (float*)(ws + 335544320);

    hipMemsetAsync(rowsum, 0, (size_t)B_ * N_ * 4, stream);
    k0_transpose<<<dim3(512, 16), 256, 0, stream>>>(feat, fT);
    k1_xgemm   <<<dim3(256, 8),  256, 0, stream>>>(feat, W, bias, x_hi, x_lo);
    k2_scores  <<<dim3(256, 16), 256, 0, stream>>>(feat, x_hi, x_lo, lengths, P, rowsum);
    k3_pv      <<<dim3(128, 16), 256, 0, stream>>>(P, fT, rowsum, lengths, out);
}

// Round 3
// 925.824 us; speedup vs baseline: 1.3650x; 1.3650x over previous
//
#include <hip/hip_runtime.h>
#include <stdint.h>

#define B_ 16
#define N_ 2048
#define V_ 1024

typedef __bf16 bf16x8 __attribute__((ext_vector_type(8)));
typedef float  f32x4  __attribute__((ext_vector_type(4)));

__device__ __forceinline__ unsigned short f2bf(float f) {
    union { float f; uint32_t u; } c; c.f = f;
    uint32_t r = c.u + 0x7fffu + ((c.u >> 16) & 1u);   // RNE
    return (unsigned short)(r >> 16);
}
__device__ __forceinline__ float bf2f(unsigned short h) {
    union { uint32_t u; float f; } c; c.u = ((uint32_t)h) << 16;
    return c.f;
}
__device__ __forceinline__ void gld_lds16(const void* g, void* l) {
    __builtin_amdgcn_global_load_lds(
        (const __attribute__((address_space(1))) void*)g,
        (__attribute__((address_space(3))) void*)l, 16, 0, 0);
}

// ---------------- kw: W -> W_hi / W_lo (bf16 split) ----------------
__global__ __launch_bounds__(256) void kw_split(
    const float* __restrict__ W, unsigned short* __restrict__ Wh, unsigned short* __restrict__ Wl)
{
    int idx = blockIdx.x * 256 + threadIdx.x;      // 4 floats per thread
    float4 f = *(const float4*)(W + (size_t)idx * 4);
    unsigned short h0 = f2bf(f.x), h1 = f2bf(f.y), h2 = f2bf(f.z), h3 = f2bf(f.w);
    *(ushort4*)(Wh + (size_t)idx * 4) = make_ushort4(h0, h1, h2, h3);
    *(ushort4*)(Wl + (size_t)idx * 4) = make_ushort4(
        f2bf(f.x - bf2f(h0)), f2bf(f.y - bf2f(h1)),
        f2bf(f.z - bf2f(h2)), f2bf(f.w - bf2f(h3)));
}

// ---------------- K0: feat -> feat_hi/feat_lo (row-major) + fT (transposed hi) ----------------
__global__ __launch_bounds__(256) void k0_prep(
    const float* __restrict__ feat, unsigned short* __restrict__ fh,
    unsigned short* __restrict__ fl, unsigned short* __restrict__ fT)
{
    __shared__ __align__(16) unsigned short T[64 * 66];  // +2 pad breaks transpose bank conflicts
    const int b  = blockIdx.y;
    const int tm = blockIdx.x & 31, tv = blockIdx.x >> 5;
    const int m0 = tm * 64, v0 = tv * 64;
    const size_t bN = (size_t)b * N_;
    const int tid = threadIdx.x;

    for (int it = 0; it < 4; ++it) {
        int idx = tid + 256 * it;
        int mm = idx >> 4, vseg = idx & 15;
        size_t goff = (bN + m0 + mm) * V_ + v0 + vseg * 4;
        float4 f4 = *(const float4*)(feat + goff);
        unsigned short h0 = f2bf(f4.x), h1 = f2bf(f4.y), h2 = f2bf(f4.z), h3 = f2bf(f4.w);
        *(ushort2*)&T[mm * 66 + vseg * 4]     = make_ushort2(h0, h1);
        *(ushort2*)&T[mm * 66 + vseg * 4 + 2] = make_ushort2(h2, h3);
        *(ushort4*)(fh + goff) = make_ushort4(h0, h1, h2, h3);
        *(ushort4*)(fl + goff) = make_ushort4(
            f2bf(f4.x - bf2f(h0)), f2bf(f4.y - bf2f(h1)),
            f2bf(f4.z - bf2f(h2)), f2bf(f4.w - bf2f(h3)));
    }
    __syncthreads();
    for (int it = 0; it < 2; ++it) {
        int idx = tid + 256 * it;
        int vv = idx >> 3, mseg = idx & 7;
        uint4 pk;
        unsigned short* pp = (unsigned short*)&pk;
        #pragma unroll
        for (int j = 0; j < 8; ++j) pp[j] = T[(mseg * 8 + j) * 66 + vv];
        *(uint4*)&fT[(size_t)b * V_ * N_ + (size_t)(v0 + vv) * N_ + m0 + mseg * 8] = pk;
    }
}

// ---------------- K1: x = feat @ W^T + b, split-bf16, all-gload_lds staging ----------------
__global__ __launch_bounds__(256, 2) void k1_xgemm(
    const unsigned short* __restrict__ fh, const unsigned short* __restrict__ fl,
    const unsigned short* __restrict__ Wh, const unsigned short* __restrict__ Wl,
    const float* __restrict__ bias,
    unsigned short* __restrict__ x_hi, unsigned short* __restrict__ x_lo)
{
    __shared__ __align__(16) unsigned short Ah[128 * 64], Al[128 * 64], Bh[128 * 64], Bl[128 * 64];
    const int tid = threadIdx.x;
    const int lane = tid & 63, wid = tid >> 6;
    const int wr = wid >> 1, wc = wid & 1;
    const int l15 = lane & 15, lg = lane >> 4;
    const size_t gm0 = (size_t)blockIdx.x * 128;
    const int o0 = blockIdx.y * 128;

    f32x4 acc[4][4];
    #pragma unroll
    for (int i = 0; i < 4; ++i)
        #pragma unroll
        for (int j = 0; j < 4; ++j) acc[i][j] = (f32x4)(0.0f);

    for (int kk = 0; kk < V_; kk += 64) {
        #pragma unroll
        for (int i = 0; i < 4; ++i) {
            int chunk = wid * 4 + i;            // wave-uniform LDS base; per-lane global addr
            int lidx = chunk * 64 + lane;
            int row = lidx >> 3, seg = lidx & 7;
            size_t ga = (gm0 + row) * V_ + kk + seg * 8;
            size_t gb = (size_t)(o0 + row) * V_ + kk + seg * 8;
            gld_lds16(fh + ga, &Ah[chunk * 512]);
            gld_lds16(fl + ga, &Al[chunk * 512]);
            gld_lds16(Wh + gb, &Bh[chunk * 512]);
            gld_lds16(Wl + gb, &Bl[chunk * 512]);
        }
        __syncthreads();
        #pragma unroll
        for (int kq = 0; kq < 2; ++kq) {
            bf16x8 ah[4], al[4], bh[4], bl[4];
            #pragma unroll
            for (int i = 0; i < 4; ++i) {
                int ra = wr * 64 + i * 16 + l15;
                ah[i] = *(const bf16x8*)&Ah[ra * 64 + kq * 32 + lg * 8];
                al[i] = *(const bf16x8*)&Al[ra * 64 + kq * 32 + lg * 8];
                int rb = wc * 64 + i * 16 + l15;
                bh[i] = *(const bf16x8*)&Bh[rb * 64 + kq * 32 + lg * 8];
                bl[i] = *(const bf16x8*)&Bl[rb * 64 + kq * 32 + lg * 8];
            }
            #pragma unroll
            for (int i = 0; i < 4; ++i)
                #pragma unroll
                for (int j = 0; j < 4; ++j) {
                    acc[i][j] = __builtin_amdgcn_mfma_f32_16x16x32_bf16(ah[i], bh[j], acc[i][j], 0, 0, 0);
                    acc[i][j] = __builtin_amdgcn_mfma_f32_16x16x32_bf16(al[i], bh[j], acc[i][j], 0, 0, 0);
                    acc[i][j] = __builtin_amdgcn_mfma_f32_16x16x32_bf16(ah[i], bl[j], acc[i][j], 0, 0, 0);
                }
        }
        __syncthreads();
    }
    #pragma unroll
    for (int j = 0; j < 4; ++j) {
        int oc = o0 + wc * 64 + j * 16 + l15;
        float bv = bias[oc];
        #pragma unroll
        for (int i = 0; i < 4; ++i)
            #pragma unroll
            for (int r = 0; r < 4; ++r) {
                size_t gm = gm0 + wr * 64 + i * 16 + 4 * lg + r;
                float v = acc[i][j][r] + bv;
                unsigned short h = f2bf(v);
                x_hi[gm * V_ + oc] = h;
                x_lo[gm * V_ + oc] = f2bf(v - bf2f(h));
            }
    }
}

// ---------------- K2: P = mask * exp(tanh(x f^T)), rowsum += ----------------
__global__ __launch_bounds__(256, 2) void k2_scores(
    const float* __restrict__ feat,
    const unsigned short* __restrict__ x_hi, const unsigned short* __restrict__ x_lo,
    const int* __restrict__ lengths,
    unsigned short* __restrict__ P, float* __restrict__ rowsum)
{
    __shared__ __align__(16) unsigned short Ah[128 * 64], Al[128 * 64], Bh[128 * 64], Bl[128 * 64];
    const int b = blockIdx.y;
    const int tn = blockIdx.x & 15, tm = blockIdx.x >> 4;
    const int n0 = tn * 128, m0 = tm * 128;
    const int len = lengths[b];
    const int m_end = min(n0 + 128, len);
    if (m0 >= m_end) return;  // tile fully masked (uniform exit, before barriers)

    const int tid = threadIdx.x;
    const int lane = tid & 63, wid = tid >> 6;
    const int wr = wid >> 1, wc = wid & 1;
    const int l15 = lane & 15, lg = lane >> 4;
    const size_t bN = (size_t)b * N_;

    f32x4 acc[4][4];
    #pragma unroll
    for (int i = 0; i < 4; ++i)
        #pragma unroll
        for (int j = 0; j < 4; ++j) acc[i][j] = (f32x4)(0.0f);

    for (int kk = 0; kk < V_; kk += 64) {
        // A: x_hi/x_lo via async global->LDS (linear dest, 16B/lane)
        #pragma unroll
        for (int i = 0; i < 4; ++i) {
            int chunk = wid * 4 + i;
            int lidx = chunk * 64 + lane;
            int row = lidx >> 3, seg = lidx & 7;
            gld_lds16(x_hi + (bN + n0 + row) * V_ + kk + seg * 8, &Ah[chunk * 512]);
            gld_lds16(x_lo + (bN + n0 + row) * V_ + kk + seg * 8, &Al[chunk * 512]);
        }
        // B: features fp32 -> hi/lo split in LDS (feat_hi/lo already overwritten by P region)
        #pragma unroll
        for (int it = 0; it < 8; ++it) {
            int idx = tid + 256 * it;
            int row = idx >> 4, seg = idx & 15;
            float4 fb = *(const float4*)(feat + (bN + m0 + row) * V_ + kk + seg * 4);
            unsigned short g0 = f2bf(fb.x), g1 = f2bf(fb.y), g2 = f2bf(fb.z), g3 = f2bf(fb.w);
            *(ushort4*)&Bh[row * 64 + seg * 4] = make_ushort4(g0, g1, g2, g3);
            *(ushort4*)&Bl[row * 64 + seg * 4] = make_ushort4(
                f2bf(fb.x - bf2f(g0)), f2bf(fb.y - bf2f(g1)),
                f2bf(fb.z - bf2f(g2)), f2bf(fb.w - bf2f(g3)));
        }
        __syncthreads();
        #pragma unroll
        for (int kq = 0; kq < 2; ++kq) {
            bf16x8 ah[4], al[4], bh[4], bl[4];
            #pragma unroll
            for (int i = 0; i < 4; ++i) {
                int ra = wr * 64 + i * 16 + l15;
                ah[i] = *(const bf16x8*)&Ah[ra * 64 + kq * 32 + lg * 8];
                al[i] = *(const bf16x8*)&Al[ra * 64 + kq * 32 + lg * 8];
                int rb = wc * 64 + i * 16 + l15;
                bh[i] = *(const bf16x8*)&Bh[rb * 64 + kq * 32 + lg * 8];
                bl[i] = *(const bf16x8*)&Bl[rb * 64 + kq * 32 + lg * 8];
            }
            #pragma unroll
            for (int i = 0; i < 4; ++i)
                #pragma unroll
                for (int j = 0; j < 4; ++j) {
                    acc[i][j] = __builtin_amdgcn_mfma_f32_16x16x32_bf16(ah[i], bh[j], acc[i][j], 0, 0, 0);
                    acc[i][j] = __builtin_amdgcn_mfma_f32_16x16x32_bf16(al[i], bh[j], acc[i][j], 0, 0, 0);
                    acc[i][j] = __builtin_amdgcn_mfma_f32_16x16x32_bf16(ah[i], bl[j], acc[i][j], 0, 0, 0);
                }
        }
        __syncthreads();
    }

    // epilogue: p = exp(tanh(s)) masked; store bf16 P; accumulate fp32 rowsum
    unsigned short* Pb = P + (size_t)b * N_ * N_;
    #pragma unroll
    for (int i = 0; i < 4; ++i) {
        float prow[4] = {0.f, 0.f, 0.f, 0.f};
        #pragma unroll
        for (int j = 0; j < 4; ++j) {
            int mg = m0 + wc * 64 + j * 16 + l15;
            #pragma unroll
            for (int r = 0; r < 4; ++r) {
                int ng = n0 + wr * 64 + i * 16 + 4 * lg + r;
                float s = acc[i][j][r];
                float e2 = __expf(2.0f * fabsf(s));
                float t = 1.0f - __fdividef(2.0f, e2 + 1.0f);   // tanh(|s|), exact at inf
                t = (s < 0.0f) ? -t : t;
                float p = __expf(t);
                bool keep = (mg <= ng) && (mg < len);
                p = keep ? p : 0.0f;
                unsigned short ph = f2bf(p);
                Pb[(size_t)ng * N_ + mg] = ph;
                prow[r] += bf2f(ph);   // sum the ROUNDED value so weights renormalize exactly
            }
        }
        #pragma unroll
        for (int r = 0; r < 4; ++r) {
            float v = prow[r];
            v += __shfl_xor(v, 1); v += __shfl_xor(v, 2);
            v += __shfl_xor(v, 4); v += __shfl_xor(v, 8);
            if (l15 == 0) {
                int ng = n0 + wr * 64 + i * 16 + 4 * lg + r;
                atomicAdd(&rowsum[bN + ng], v);
            }
        }
    }
}

// ---------------- K3: out = (P @ f) / rowsum ----------------
__global__ __launch_bounds__(256, 2) void k3_pv(
    const unsigned short* __restrict__ P, const unsigned short* __restrict__ fT,
    const float* __restrict__ rowsum, const int* __restrict__ lengths,
    float* __restrict__ out)
{
    __shared__ __align__(16) unsigned short Ap[128 * 64], Bp[128 * 64];
    const int b = blockIdx.y;
    const int tn = blockIdx.x & 15, tv = blockIdx.x >> 4;
    const int n0 = tn * 128, v0 = tv * 128;
    const int len = lengths[b];
    const int m_end = min(n0 + 128, len);
    const int nk = (m_end + 63) >> 6;
    const size_t bN = (size_t)b * N_;
    const unsigned short* Pb  = P  + (size_t)b * N_ * N_;
    const unsigned short* fTb = fT + (size_t)b * V_ * N_;

    const int tid = threadIdx.x;
    const int lane = tid & 63, wid = tid >> 6;
    const int wr = wid >> 1, wc = wid & 1;
    const int l15 = lane & 15, lg = lane >> 4;

    f32x4 acc[4][4];
    #pragma unroll
    for (int i = 0; i < 4; ++i)
        #pragma unroll
        for (int j = 0; j < 4; ++j) acc[i][j] = (f32x4)(0.0f);

    for (int kt = 0; kt < nk; ++kt) {
        int k0 = kt * 64;
        #pragma unroll
        for (int i = 0; i < 4; ++i) {
            int chunk = wid * 4 + i;
            int lidx = chunk * 64 + lane;
            int row = lidx >> 3, seg = lidx & 7;
            gld_lds16(Pb  + (size_t)(n0 + row) * N_ + k0 + seg * 8, &Ap[chunk * 512]);
            gld_lds16(fTb + (size_t)(v0 + row) * N_ + k0 + seg * 8, &Bp[chunk * 512]);
        }
        __syncthreads();
        #pragma unroll
        for (int kq = 0; kq < 2; ++kq) {
            bf16x8 a[4], bb[4];
            #pragma unroll
            for (int i = 0; i < 4; ++i) {
                int ra = wr * 64 + i * 16 + l15;
                a[i]  = *(const bf16x8*)&Ap[ra * 64 + kq * 32 + lg * 8];
                int rb = wc * 64 + i * 16 + l15;
                bb[i] = *(const bf16x8*)&Bp[rb * 64 + kq * 32 + lg * 8];
            }
            #pragma unroll
            for (int i = 0; i < 4; ++i)
                #pragma unroll
                for (int j = 0; j < 4; ++j)
                    acc[i][j] = __builtin_amdgcn_mfma_f32_16x16x32_bf16(a[i], bb[j], acc[i][j], 0, 0, 0);
        }
        __syncthreads();
    }

    #pragma unroll
    for (int i = 0; i < 4; ++i)
        #pragma unroll
        for (int r = 0; r < 4; ++r) {
            int ng = n0 + wr * 64 + i * 16 + 4 * lg + r;
            float rinv = 1.0f / rowsum[bN + ng];
            #pragma unroll
            for (int j = 0; j < 4; ++j) {
                int vg = v0 + wc * 64 + j * 16 + l15;
                out[(bN + ng) * (size_t)V_ + vg] = acc[i][j][r] * rinv;
            }
        }
}

extern "C" void kernel_launch(void* const* d_in, const int* in_sizes, int n_in,
                              void* d_out, int out_size, void* d_ws, size_t ws_size,
                              hipStream_t stream)
{
    const float* feat    = (const float*)d_in[0];
    const int*   lengths = (const int*)d_in[1];
    const float* W       = (const float*)d_in[2];
    const float* bias    = (const float*)d_in[3];
    float* out = (float*)d_out;

    char* ws = (char*)d_ws;
    // ws layout (bytes), with lifetime overlap:
    //   [0, 128MB):       feat_hi (64MB) + feat_lo (64MB)   -- live K0..K1
    //                     P (128MB)                          -- live K2..K3 (overlaps feat_hi/lo)
    //   [128MB, 192MB):   x_hi
    //   [192MB, 256MB):   x_lo
    //   [256MB, 320MB):   fT
    //   [320MB, +2MB):    W_hi
    //   [+2MB, +2MB):     W_lo
    //   then rowsum (128KB).  Total ~324 MiB.
    unsigned short* feat_hi = (unsigned short*)(ws);
    unsigned short* feat_lo = (unsigned short*)(ws + 67108864);
    unsigned short* P       = (unsigned short*)(ws);            // overlaps feat_hi/lo
    unsigned short* x_hi    = (unsigned short*)(ws + 134217728);
    unsigned short* x_lo    = (unsigned short*)(ws + 201326592);
    unsigned short* fT      = (unsigned short*)(ws + 268435456);
    unsigned short* W_hi    = (unsigned short*)(ws + 335544320);
    unsigned short* W_lo    = (unsigned short*)(ws + 337641472);
    float* rowsum           = (float*)(ws + 339738624);

    hipMemsetAsync(rowsum, 0, (size_t)B_ * N_ * 4, stream);
    kw_split   <<<dim3(1024),     256, 0, stream>>>(W, W_hi, W_lo);
    k0_prep    <<<dim3(512, 16),  256, 0, stream>>>(feat, feat_hi, feat_lo, fT);
    k1_xgemm   <<<dim3(256, 8),   256, 0, stream>>>(feat_hi, feat_lo, W_hi, W_lo, bias, x_hi, x_lo);
    k2_scores  <<<dim3(256, 16),  256, 0, stream>>>(feat, x_hi, x_lo, lengths, P, rowsum);
    k3_pv      <<<dim3(128, 16),  256, 0, stream>>>(P, fT, rowsum, lengths, out);
}

// Round 5
// 882.211 us; speedup vs baseline: 1.4325x; 1.0494x over previous
//
#include <hip/hip_runtime.h>
#include <stdint.h>

#define B_ 16
#define N_ 2048
#define V_ 1024

typedef __bf16 bf16x8 __attribute__((ext_vector_type(8)));
typedef float  f32x4  __attribute__((ext_vector_type(4)));

__device__ __forceinline__ unsigned short f2bf(float f) {
    union { float f; uint32_t u; } c; c.f = f;
    uint32_t r = c.u + 0x7fffu + ((c.u >> 16) & 1u);   // RNE
    return (unsigned short)(r >> 16);
}
__device__ __forceinline__ float bf2f(unsigned short h) {
    union { uint32_t u; float f; } c; c.u = ((uint32_t)h) << 16;
    return c.f;
}
__device__ __forceinline__ void gld_lds16(const void* g, void* l) {
    __builtin_amdgcn_global_load_lds(
        (const __attribute__((address_space(1))) void*)g,
        (__attribute__((address_space(3))) void*)l, 16, 0, 0);
}

// packed causal P: per batch, tiles (tn,tm) with tm<=tn, 136 tiles of 128x128 bf16
__device__ __forceinline__ size_t p_tile_base(int b, int tn, int tm) {
    return ((size_t)b * 136 + (size_t)((tn * (tn + 1)) >> 1) + tm) << 14;  // *128*128
}

// ---------------- kw: W -> W_hi / W_lo (bf16 split) ----------------
__global__ __launch_bounds__(256) void kw_split(
    const float* __restrict__ W, unsigned short* __restrict__ Wh, unsigned short* __restrict__ Wl)
{
    int idx = blockIdx.x * 256 + threadIdx.x;      // 4 floats per thread
    float4 f = *(const float4*)(W + (size_t)idx * 4);
    unsigned short h0 = f2bf(f.x), h1 = f2bf(f.y), h2 = f2bf(f.z), h3 = f2bf(f.w);
    *(ushort4*)(Wh + (size_t)idx * 4) = make_ushort4(h0, h1, h2, h3);
    *(ushort4*)(Wl + (size_t)idx * 4) = make_ushort4(
        f2bf(f.x - bf2f(h0)), f2bf(f.y - bf2f(h1)),
        f2bf(f.z - bf2f(h2)), f2bf(f.w - bf2f(h3)));
}

// ---------------- K0: feat -> feat_hi/feat_lo (row-major) + fT (transposed hi) ----------------
__global__ __launch_bounds__(256) void k0_prep(
    const float* __restrict__ feat, unsigned short* __restrict__ fh,
    unsigned short* __restrict__ fl, unsigned short* __restrict__ fT)
{
    __shared__ __align__(16) unsigned short T[64 * 66];  // +2 pad breaks transpose bank conflicts
    const int b  = blockIdx.y;
    const int tm = blockIdx.x & 31, tv = blockIdx.x >> 5;
    const int m0 = tm * 64, v0 = tv * 64;
    const size_t bN = (size_t)b * N_;
    const int tid = threadIdx.x;

    for (int it = 0; it < 4; ++it) {
        int idx = tid + 256 * it;
        int mm = idx >> 4, vseg = idx & 15;
        size_t goff = (bN + m0 + mm) * V_ + v0 + vseg * 4;
        float4 f4 = *(const float4*)(feat + goff);
        unsigned short h0 = f2bf(f4.x), h1 = f2bf(f4.y), h2 = f2bf(f4.z), h3 = f2bf(f4.w);
        *(ushort2*)&T[mm * 66 + vseg * 4]     = make_ushort2(h0, h1);
        *(ushort2*)&T[mm * 66 + vseg * 4 + 2] = make_ushort2(h2, h3);
        *(ushort4*)(fh + goff) = make_ushort4(h0, h1, h2, h3);
        *(ushort4*)(fl + goff) = make_ushort4(
            f2bf(f4.x - bf2f(h0)), f2bf(f4.y - bf2f(h1)),
            f2bf(f4.z - bf2f(h2)), f2bf(f4.w - bf2f(h3)));
    }
    __syncthreads();
    for (int it = 0; it < 2; ++it) {
        int idx = tid + 256 * it;
        int vv = idx >> 3, mseg = idx & 7;
        uint4 pk;
        unsigned short* pp = (unsigned short*)&pk;
        #pragma unroll
        for (int j = 0; j < 8; ++j) pp[j] = T[(mseg * 8 + j) * 66 + vv];
        *(uint4*)&fT[(size_t)b * V_ * N_ + (size_t)(v0 + vv) * N_ + m0 + mseg * 8] = pk;
    }
}

// ---------------- K1: x = feat @ W^T + b, split-bf16, all-gload_lds staging ----------------
__global__ __launch_bounds__(256, 2) void k1_xgemm(
    const unsigned short* __restrict__ fh, const unsigned short* __restrict__ fl,
    const unsigned short* __restrict__ Wh, const unsigned short* __restrict__ Wl,
    const float* __restrict__ bias,
    unsigned short* __restrict__ x_hi, unsigned short* __restrict__ x_lo)
{
    __shared__ __align__(16) unsigned short Ah[128 * 64], Al[128 * 64], Bh[128 * 64], Bl[128 * 64];
    const int tid = threadIdx.x;
    const int lane = tid & 63, wid = tid >> 6;
    const int wr = wid >> 1, wc = wid & 1;
    const int l15 = lane & 15, lg = lane >> 4;
    const size_t gm0 = (size_t)blockIdx.x * 128;
    const int o0 = blockIdx.y * 128;

    f32x4 acc[4][4];
    #pragma unroll
    for (int i = 0; i < 4; ++i)
        #pragma unroll
        for (int j = 0; j < 4; ++j) acc[i][j] = (f32x4)(0.0f);

    for (int kk = 0; kk < V_; kk += 64) {
        #pragma unroll
        for (int i = 0; i < 4; ++i) {
            int chunk = wid * 4 + i;            // wave-uniform LDS base; per-lane global addr
            int lidx = chunk * 64 + lane;
            int row = lidx >> 3, seg = lidx & 7;
            size_t ga = (gm0 + row) * V_ + kk + seg * 8;
            size_t gb = (size_t)(o0 + row) * V_ + kk + seg * 8;
            gld_lds16(fh + ga, &Ah[chunk * 512]);
            gld_lds16(fl + ga, &Al[chunk * 512]);
            gld_lds16(Wh + gb, &Bh[chunk * 512]);
            gld_lds16(Wl + gb, &Bl[chunk * 512]);
        }
        __syncthreads();
        #pragma unroll
        for (int kq = 0; kq < 2; ++kq) {
            bf16x8 ah[4], al[4], bh[4], bl[4];
            #pragma unroll
            for (int i = 0; i < 4; ++i) {
                int ra = wr * 64 + i * 16 + l15;
                ah[i] = *(const bf16x8*)&Ah[ra * 64 + kq * 32 + lg * 8];
                al[i] = *(const bf16x8*)&Al[ra * 64 + kq * 32 + lg * 8];
                int rb = wc * 64 + i * 16 + l15;
                bh[i] = *(const bf16x8*)&Bh[rb * 64 + kq * 32 + lg * 8];
                bl[i] = *(const bf16x8*)&Bl[rb * 64 + kq * 32 + lg * 8];
            }
            #pragma unroll
            for (int i = 0; i < 4; ++i)
                #pragma unroll
                for (int j = 0; j < 4; ++j) {
                    acc[i][j] = __builtin_amdgcn_mfma_f32_16x16x32_bf16(ah[i], bh[j], acc[i][j], 0, 0, 0);
                    acc[i][j] = __builtin_amdgcn_mfma_f32_16x16x32_bf16(al[i], bh[j], acc[i][j], 0, 0, 0);
                    acc[i][j] = __builtin_amdgcn_mfma_f32_16x16x32_bf16(ah[i], bl[j], acc[i][j], 0, 0, 0);
                }
        }
        __syncthreads();
    }
    #pragma unroll
    for (int j = 0; j < 4; ++j) {
        int oc = o0 + wc * 64 + j * 16 + l15;
        float bv = bias[oc];
        #pragma unroll
        for (int i = 0; i < 4; ++i)
            #pragma unroll
            for (int r = 0; r < 4; ++r) {
                size_t gm = gm0 + wr * 64 + i * 16 + 4 * lg + r;
                float v = acc[i][j][r] + bv;
                unsigned short h = f2bf(v);
                x_hi[gm * V_ + oc] = h;
                x_lo[gm * V_ + oc] = f2bf(v - bf2f(h));
            }
    }
}

// ---------------- K2: P = mask * exp(tanh(x f^T)), rowsum +=  (packed causal P) ----------------
// PRE=true: B-side staged from pre-split feat_hi/feat_lo via global_load_lds (fast path).
// PRE=false: B-side converted fp32->hi/lo in VALU (fallback when ws too small for both P and feat splits).
template <bool PRE>
__global__ __launch_bounds__(256, 2) void k2_scores(
    const float* __restrict__ feat,
    const unsigned short* __restrict__ fh, const unsigned short* __restrict__ fl,
    const unsigned short* __restrict__ x_hi, const unsigned short* __restrict__ x_lo,
    const int* __restrict__ lengths,
    unsigned short* __restrict__ P, float* __restrict__ rowsum)
{
    __shared__ __align__(16) unsigned short Ah[128 * 64], Al[128 * 64], Bh[128 * 64], Bl[128 * 64];
    const int b = blockIdx.y;
    const int tn = blockIdx.x & 15, tm = blockIdx.x >> 4;
    const int n0 = tn * 128, m0 = tm * 128;
    const int len = lengths[b];
    const int m_end = min(n0 + 128, len);
    if (m0 >= m_end) return;  // fully masked or acausal tile (uniform exit, before barriers)

    const int tid = threadIdx.x;
    const int lane = tid & 63, wid = tid >> 6;
    const int wr = wid >> 1, wc = wid & 1;
    const int l15 = lane & 15, lg = lane >> 4;
    const size_t bN = (size_t)b * N_;

    f32x4 acc[4][4];
    #pragma unroll
    for (int i = 0; i < 4; ++i)
        #pragma unroll
        for (int j = 0; j < 4; ++j) acc[i][j] = (f32x4)(0.0f);

    for (int kk = 0; kk < V_; kk += 64) {
        if constexpr (PRE) {
            #pragma unroll
            for (int i = 0; i < 4; ++i) {
                int chunk = wid * 4 + i;
                int lidx = chunk * 64 + lane;
                int row = lidx >> 3, seg = lidx & 7;
                size_t ga = (bN + n0 + row) * V_ + kk + seg * 8;
                size_t gb = (bN + m0 + row) * V_ + kk + seg * 8;
                gld_lds16(x_hi + ga, &Ah[chunk * 512]);
                gld_lds16(x_lo + ga, &Al[chunk * 512]);
                gld_lds16(fh + gb, &Bh[chunk * 512]);
                gld_lds16(fl + gb, &Bl[chunk * 512]);
            }
        } else {
            #pragma unroll
            for (int i = 0; i < 4; ++i) {
                int chunk = wid * 4 + i;
                int lidx = chunk * 64 + lane;
                int row = lidx >> 3, seg = lidx & 7;
                gld_lds16(x_hi + (bN + n0 + row) * V_ + kk + seg * 8, &Ah[chunk * 512]);
                gld_lds16(x_lo + (bN + n0 + row) * V_ + kk + seg * 8, &Al[chunk * 512]);
            }
            #pragma unroll
            for (int it = 0; it < 8; ++it) {
                int idx = tid + 256 * it;
                int row = idx >> 4, seg = idx & 15;
                float4 fb = *(const float4*)(feat + (bN + m0 + row) * V_ + kk + seg * 4);
                unsigned short g0 = f2bf(fb.x), g1 = f2bf(fb.y), g2 = f2bf(fb.z), g3 = f2bf(fb.w);
                *(ushort4*)&Bh[row * 64 + seg * 4] = make_ushort4(g0, g1, g2, g3);
                *(ushort4*)&Bl[row * 64 + seg * 4] = make_ushort4(
                    f2bf(fb.x - bf2f(g0)), f2bf(fb.y - bf2f(g1)),
                    f2bf(fb.z - bf2f(g2)), f2bf(fb.w - bf2f(g3)));
            }
        }
        __syncthreads();
        #pragma unroll
        for (int kq = 0; kq < 2; ++kq) {
            bf16x8 ah[4], al[4], bh[4], bl[4];
            #pragma unroll
            for (int i = 0; i < 4; ++i) {
                int ra = wr * 64 + i * 16 + l15;
                ah[i] = *(const bf16x8*)&Ah[ra * 64 + kq * 32 + lg * 8];
                al[i] = *(const bf16x8*)&Al[ra * 64 + kq * 32 + lg * 8];
                int rb = wc * 64 + i * 16 + l15;
                bh[i] = *(const bf16x8*)&Bh[rb * 64 + kq * 32 + lg * 8];
                bl[i] = *(const bf16x8*)&Bl[rb * 64 + kq * 32 + lg * 8];
            }
            #pragma unroll
            for (int i = 0; i < 4; ++i)
                #pragma unroll
                for (int j = 0; j < 4; ++j) {
                    acc[i][j] = __builtin_amdgcn_mfma_f32_16x16x32_bf16(ah[i], bh[j], acc[i][j], 0, 0, 0);
                    acc[i][j] = __builtin_amdgcn_mfma_f32_16x16x32_bf16(al[i], bh[j], acc[i][j], 0, 0, 0);
                    acc[i][j] = __builtin_amdgcn_mfma_f32_16x16x32_bf16(ah[i], bl[j], acc[i][j], 0, 0, 0);
                }
        }
        __syncthreads();
    }

    // epilogue: p = exp(tanh(s)) masked; store bf16 packed P; accumulate fp32 rowsum
    unsigned short* Pt = P + p_tile_base(b, tn, tm);
    #pragma unroll
    for (int i = 0; i < 4; ++i) {
        float prow[4] = {0.f, 0.f, 0.f, 0.f};
        #pragma unroll
        for (int j = 0; j < 4; ++j) {
            int mi = wc * 64 + j * 16 + l15;          // m within tile
            int mg = m0 + mi;
            #pragma unroll
            for (int r = 0; r < 4; ++r) {
                int ni = wr * 64 + i * 16 + 4 * lg + r;  // n within tile
                int ng = n0 + ni;
                float s = acc[i][j][r];
                float e2 = __expf(2.0f * fabsf(s));
                float t = 1.0f - __fdividef(2.0f, e2 + 1.0f);   // tanh(|s|), exact at inf
                t = (s < 0.0f) ? -t : t;
                float p = __expf(t);
                bool keep = (mg <= ng) && (mg < len);
                p = keep ? p : 0.0f;
                unsigned short ph = f2bf(p);
                Pt[(size_t)ni * 128 + mi] = ph;
                prow[r] += bf2f(ph);   // sum the ROUNDED value so weights renormalize exactly
            }
        }
        #pragma unroll
        for (int r = 0; r < 4; ++r) {
            float v = prow[r];
            v += __shfl_xor(v, 1); v += __shfl_xor(v, 2);
            v += __shfl_xor(v, 4); v += __shfl_xor(v, 8);
            if (l15 == 0) {
                int ng = n0 + wr * 64 + i * 16 + 4 * lg + r;
                atomicAdd(&rowsum[bN + ng], v);
            }
        }
    }
}

// ---------------- K3: out = (P @ f) / rowsum  (packed causal P) ----------------
__global__ __launch_bounds__(256, 2) void k3_pv(
    const unsigned short* __restrict__ P, const unsigned short* __restrict__ fT,
    const float* __restrict__ rowsum, const int* __restrict__ lengths,
    float* __restrict__ out)
{
    __shared__ __align__(16) unsigned short Ap[128 * 64], Bp[128 * 64];
    const int b = blockIdx.y;
    const int tn = blockIdx.x & 15, tv = blockIdx.x >> 4;
    const int n0 = tn * 128, v0 = tv * 128;
    const int len = lengths[b];
    const int m_end = min(n0 + 128, len);
    const int nk = (m_end + 63) >> 6;
    const size_t bN = (size_t)b * N_;
    const size_t triBase = p_tile_base(b, tn, 0);
    const unsigned short* fTb = fT + (size_t)b * V_ * N_;

    const int tid = threadIdx.x;
    const int lane = tid & 63, wid = tid >> 6;
    const int wr = wid >> 1, wc = wid & 1;
    const int l15 = lane & 15, lg = lane >> 4;

    f32x4 acc[4][4];
    #pragma unroll
    for (int i = 0; i < 4; ++i)
        #pragma unroll
        for (int j = 0; j < 4; ++j) acc[i][j] = (f32x4)(0.0f);

    for (int kt = 0; kt < nk; ++kt) {
        int k0 = kt * 64;
        int tmk = kt >> 1, half = kt & 1;
        const unsigned short* Ptile = P + triBase + ((size_t)tmk << 14);
        #pragma unroll
        for (int i = 0; i < 4; ++i) {
            int chunk = wid * 4 + i;
            int lidx = chunk * 64 + lane;
            int row = lidx >> 3, seg = lidx & 7;
            gld_lds16(Ptile + (size_t)row * 128 + half * 64 + seg * 8, &Ap[chunk * 512]);
            gld_lds16(fTb + (size_t)(v0 + row) * N_ + k0 + seg * 8, &Bp[chunk * 512]);
        }
        __syncthreads();
        #pragma unroll
        for (int kq = 0; kq < 2; ++kq) {
            bf16x8 a[4], bb[4];
            #pragma unroll
            for (int i = 0; i < 4; ++i) {
                int ra = wr * 64 + i * 16 + l15;
                a[i]  = *(const bf16x8*)&Ap[ra * 64 + kq * 32 + lg * 8];
                int rb = wc * 64 + i * 16 + l15;
                bb[i] = *(const bf16x8*)&Bp[rb * 64 + kq * 32 + lg * 8];
            }
            #pragma unroll
            for (int i = 0; i < 4; ++i)
                #pragma unroll
                for (int j = 0; j < 4; ++j)
                    acc[i][j] = __builtin_amdgcn_mfma_f32_16x16x32_bf16(a[i], bb[j], acc[i][j], 0, 0, 0);
        }
        __syncthreads();
    }

    #pragma unroll
    for (int i = 0; i < 4; ++i)
        #pragma unroll
        for (int r = 0; r < 4; ++r) {
            int ng = n0 + wr * 64 + i * 16 + 4 * lg + r;
            float rinv = 1.0f / rowsum[bN + ng];
            #pragma unroll
            for (int j = 0; j < 4; ++j) {
                int vg = v0 + wc * 64 + j * 16 + l15;
                out[(bN + ng) * (size_t)V_ + vg] = acc[i][j][r] * rinv;
            }
        }
}

extern "C" void kernel_launch(void* const* d_in, const int* in_sizes, int n_in,
                              void* d_out, int out_size, void* d_ws, size_t ws_size,
                              hipStream_t stream)
{
    const float* feat    = (const float*)d_in[0];
    const int*   lengths = (const int*)d_in[1];
    const float* W       = (const float*)d_in[2];
    const float* bias    = (const float*)d_in[3];
    float* out = (float*)d_out;

    char* ws = (char*)d_ws;
    // Fixed skeleton (both paths):
    //   feat_hi @ 0        (64MB)   -- live K0..K1 (path A: ..K2)
    //   feat_lo @ 64MB     (64MB)
    //   x_hi    @ 128MB    (64MB)
    //   x_lo    @ 192MB    (64MB)
    //   fT      @ 256MB    (64MB)
    //   W_hi    @ 320MB    (2MB), W_lo @ +2MB, rowsum @ +2MB (128KB)
    //   P (packed causal, 68MB):
    //     path A (ws >= 392.2MB): own region @ 324.1MB  -> feat_hi/lo stay live for K2 (PRE=true)
    //     path B: overlap feat_hi/lo @ 0                -> K2 VALU-splits B from fp32 feat (PRE=false)
    unsigned short* feat_hi = (unsigned short*)(ws);
    unsigned short* feat_lo = (unsigned short*)(ws + 67108864);
    unsigned short* x_hi    = (unsigned short*)(ws + 134217728);
    unsigned short* x_lo    = (unsigned short*)(ws + 201326592);
    unsigned short* fT      = (unsigned short*)(ws + 268435456);
    unsigned short* W_hi    = (unsigned short*)(ws + 335544320);
    unsigned short* W_lo    = (unsigned short*)(ws + 337641472);
    float* rowsum           = (float*)(ws + 339738624);

    const size_t P_SEPARATE_OFF = 339869696;           // rowsum end
    const size_t P_BYTES        = 71303168;            // 16*136*128*128*2
    const bool big = ws_size >= P_SEPARATE_OFF + P_BYTES;   // 411,172,864
    unsigned short* P = big ? (unsigned short*)(ws + P_SEPARATE_OFF)
                            : (unsigned short*)(ws);

    hipMemsetAsync(rowsum, 0, (size_t)B_ * N_ * 4, stream);
    kw_split <<<dim3(1024),    256, 0, stream>>>(W, W_hi, W_lo);
    k0_prep  <<<dim3(512, 16), 256, 0, stream>>>(feat, feat_hi, feat_lo, fT);
    k1_xgemm <<<dim3(256, 8),  256, 0, stream>>>(feat_hi, feat_lo, W_hi, W_lo, bias, x_hi, x_lo);
    if (big) {
        k2_scores<true><<<dim3(256, 16), 256, 0, stream>>>(
            feat, feat_hi, feat_lo, x_hi, x_lo, lengths, P, rowsum);
    } else {
        k2_scores<false><<<dim3(256, 16), 256, 0, stream>>>(
            feat, feat_hi, feat_lo, x_hi, x_lo, lengths, P, rowsum);
    }
    k3_pv <<<dim3(128, 16), 256, 0, stream>>>(P, fT, rowsum, lengths, out);
}